// Round 11
// baseline (234.016 us; speedup 1.0000x reference)
//
#include <hip/hip_runtime.h>
#include <cstdint>

#define BATCHES 8
#define NPTS 2048
#define NF 512
#define KNN 32
#define BWAVES 4   // 256-thread block = 4 waves
#define QPW 2      // queries per wave: R1's proven pipeline (gather A || dist B)

// R11 = R1 fused kernel (best measured: 61us dispatch, VGPR 40, no spill) with
// two surgical changes driven by R10's corrected model (select=50us standalone,
// fused overlap already near-optimal, R1 grid had ZERO backfill -> 47% occ from
// drain decay):
//  1) 256-thr blocks, grid 2048: 4 resident blocks/CU (LDS 35328) + 4 QUEUED.
//     Blocks desync across phases (select=VALU/DS vs gather=VMEM) on each CU and
//     backfill kills the drain tail. Per-wave code byte-identical to R1.
//  2) merge-select: 21-round full sort64 -> 15 rounds (k=2..32) + 1 min-merge.
//     Top-32-as-set is order-invariant for maxpool; (d2,idx) keys keep ref tie
//     order. Proven correct in passing R8/R10 runs.
// Spill tripwire: WRITE_SIZE must be exactly 32768 KB; VGPR <= 64.

typedef float vfloat4 __attribute__((ext_vector_type(4)));  // native vec for nt-store

__global__ __launch_bounds__(256, 4)
void pointnetpp_knn_maxpool(const float* __restrict__ x,
                            const float* __restrict__ points,
                            float* __restrict__ out) {
    __shared__ __align__(16) float    pts4[NPTS * 4];      // [N][4]: one b128/candidate
    __shared__ __align__(16) uint64_t ckey[BWAVES][64];    // candidate keys (fast path)
    __shared__ __align__(16) int      sel[BWAVES][KNN];    // tie-fallback emit only

    const int tid  = threadIdx.x;
    const int lane = tid & 63;
    const int w    = tid >> 6;

    const int b     = blockIdx.x & 7;     // XCD-affine batch (x[b]=4MB in XCD L2)
    const int chunk = blockIdx.x >> 3;

    // ---- stage points[b] into LDS as [N][4] (pad .w) ----
    {
        const float* src = points + (size_t)b * NPTS * 3;
        for (int p = tid; p < NPTS; p += 256) {
            float4* d = (float4*)&pts4[p * 4];
            *d = make_float4(src[p * 3 + 0], src[p * 3 + 1], src[p * 3 + 2], 0.f);
        }
    }
    __syncthreads();

    const uint64_t lmlt = (1ull << lane) - 1ull;
    const float*   xb   = x + (size_t)b * NPTS * NF;

    const int iA = (chunk * BWAVES + w) * QPW;   // this wave's queries: iA, iA+1

    uint32_t db[32];   // register-reused across both queries (R1 proven shape)

    auto countLE = [&](uint32_t t) -> uint32_t {
        uint32_t c = 0;
        #pragma unroll
        for (int j = 0; j < 32; ++j)
            c += (uint32_t)__builtin_popcountll(__ballot(db[j] <= t));
        return c;
    };

    // compact <=64 candidates to LDS keys, then TOP-32 MERGE-SELECT:
    // 15 bitonic rounds (k=2..32) + 1 min-merge; lanes 0..31 end with the 32
    // smallest (d2,idx) keys (unordered; maxpool is order-invariant; set matches
    // ref tie order). Requires 32 <= cthr <= 64. [proven: R8/R10 passed]
    auto compactSelect = [&](uint32_t thr, uint32_t cthr) -> int {
        uint32_t base = 0;
        #pragma unroll
        for (int j = 0; j < 32; ++j) {
            const bool     p = db[j] <= thr;
            const uint64_t m = __ballot(p);
            if (p) {
                const int slot = (int)base + (int)__popcll(m & lmlt);
                ckey[w][slot] = (((uint64_t)db[j]) << 11) | (uint64_t)(lane + (j << 6));
            }
            base += (uint32_t)__builtin_popcountll(m);
        }
        uint64_t key = (lane < (int)cthr) ? ckey[w][lane] : ~0ull;
        #pragma unroll
        for (int k = 2; k <= 32; k <<= 1) {
            #pragma unroll
            for (int j = k >> 1; j > 0; j >>= 1) {
                const uint64_t other = __shfl_xor((unsigned long long)key, j);
                const bool takeMin = (((lane & j) == 0) == ((lane & k) == 0));
                key = ((key < other) == takeMin) ? key : other;
            }
        }
        {   // min-merge: lanes 0..31 take the 32 smallest
            const uint64_t other = __shfl_xor((unsigned long long)key, 32);
            const uint64_t mn = key < other ? key : other;
            const uint64_t mx = key < other ? other : key;
            key = ((lane & 32) == 0) ? mn : mx;
        }
        return (int)(key & 0x7FFull);
    };

    // exact-tie fallback: all <T, then ==T ascending index (ref tie order)
    auto tieFallback = [&](uint32_t T, int cnt_lt) -> int {
        int base_lt = 0, base_eq = 0;
        #pragma unroll
        for (int j = 0; j < 32; ++j) {
            const bool lt = db[j] < T;
            const bool eq = db[j] == T;
            const uint64_t mlt = __ballot(lt);
            const uint64_t meq = __ballot(eq);
            int slot = -1;
            if (lt)      slot = base_lt + (int)__popcll(mlt & lmlt);
            else if (eq) slot = cnt_lt + base_eq + (int)__popcll(meq & lmlt);
            if (slot >= 0 && slot < KNN) sel[w][slot] = lane + (j << 6);
            base_lt += (int)__popcll(mlt);
            base_eq += (int)__popcll(meq);
        }
        return sel[w][lane & (KNN - 1)];
    };

    // full select on current db[] (probe fast path + binary-search + tie fallback)
    auto selectFull = [&]() -> int {
        uint32_t lmin = db[0];
        #pragma unroll
        for (int j = 1; j < 32; ++j) lmin = min(lmin, db[j]);
        uint32_t sm = lmin;
        #pragma unroll
        for (int k = 2; k <= 64; k <<= 1) {
            #pragma unroll
            for (int j = k >> 1; j > 0; j >>= 1) {
                const uint32_t o  = (uint32_t)__shfl_xor((int)sm, j);
                const uint32_t mn = min(sm, o);
                const uint32_t mx = max(sm, o);
                sm = (((lane & j) == 0) == ((lane & k) == 0)) ? mn : mx;
            }
        }
        const uint32_t probe = (uint32_t)__builtin_amdgcn_readlane((int)sm, 31);
        const uint32_t hi0   = (uint32_t)__builtin_amdgcn_readlane((int)sm, 63);

        const uint32_t c1 = countLE(probe);          // >= 32 guaranteed
        if (c1 <= 64u) return compactSelect(probe, c1);
        const uint32_t cs = countLE(hi0);            // >= 64 guaranteed
        if (cs <= 64u) return compactSelect(hi0, cs);
        if (probe == 0u) return tieFallback(0u, 0);  // >=65 zero-distance dups
        uint32_t lo = 0u, hi = probe;                // c(lo)<32 (self only), c(hi)>64
        while (hi - lo > 1u) {
            const uint32_t mid = lo + ((hi - lo) >> 1);
            const uint32_t c   = countLE(mid);
            if (c >= KNN && c <= 64u) return compactSelect(mid, c);
            if (c > 64u) hi = mid; else lo = mid;
        }
        return tieFallback(hi, (int)countLE(lo));    // count(<=lo) == count(<hi)
    };

    // ================= query A: distances + select =================
    {
        const float4 qp = *(const float4*)&pts4[iA * 4];
        #pragma unroll
        for (int j = 0; j < 32; ++j) {
            const int n = lane + (j << 6);
            const float4 pp = *(const float4*)&pts4[n * 4];
            const float dx = qp.x - pp.x;
            const float dy = qp.y - pp.y;
            const float dz = qp.z - pp.z;
            db[j] = __float_as_uint(dx * dx + dy * dy + dz * dz);
        }
    }
    const int selvA = selectFull();

    // ===== fused: gather+maxpool A (VMEM) || distances B (VALU/LDS) =====
    // (R1's proven no-spill interleave: dist-B pairs fill the L2 shadow)
    const float4 qpB = *(const float4*)&pts4[(iA + 1) * 4];
    float4 a0 = make_float4(-INFINITY, -INFINITY, -INFINITY, -INFINITY);
    float4 a1 = a0;
    #pragma unroll   // FULL unroll: db[jj] must stay compile-time indexed (regs)
    for (int jj = 0; jj < 32; jj += 2) {
        const int n0 = __builtin_amdgcn_readlane(selvA, jj)     & (NPTS - 1);
        const int n1 = __builtin_amdgcn_readlane(selvA, jj + 1) & (NPTS - 1);
        const float4* r0 = (const float4*)(xb + (size_t)n0 * NF);
        const float4* r1 = (const float4*)(xb + (size_t)n1 * NF);
        const float4 v00 = r0[lane];
        const float4 v01 = r0[lane + 64];
        const float4 v10 = r1[lane];
        const float4 v11 = r1[lane + 64];
        {   // distance pair for query B
            const int n = lane + (jj << 6);
            const float4 p0 = *(const float4*)&pts4[n * 4];
            const float4 p1 = *(const float4*)&pts4[(n + 64) * 4];
            const float dx0 = qpB.x - p0.x, dy0 = qpB.y - p0.y, dz0 = qpB.z - p0.z;
            const float dx1 = qpB.x - p1.x, dy1 = qpB.y - p1.y, dz1 = qpB.z - p1.z;
            db[jj]     = __float_as_uint(dx0 * dx0 + dy0 * dy0 + dz0 * dz0);
            db[jj + 1] = __float_as_uint(dx1 * dx1 + dy1 * dy1 + dz1 * dz1);
        }
        a0.x = fmaxf(fmaxf(a0.x, v00.x), v10.x);
        a0.y = fmaxf(fmaxf(a0.y, v00.y), v10.y);
        a0.z = fmaxf(fmaxf(a0.z, v00.z), v10.z);
        a0.w = fmaxf(fmaxf(a0.w, v00.w), v10.w);
        a1.x = fmaxf(fmaxf(a1.x, v01.x), v11.x);
        a1.y = fmaxf(fmaxf(a1.y, v01.y), v11.y);
        a1.z = fmaxf(fmaxf(a1.z, v01.z), v11.z);
        a1.w = fmaxf(fmaxf(a1.w, v01.w), v11.w);
    }
    {
        vfloat4* orow = (vfloat4*)(out + ((size_t)b * NPTS + iA) * NF);
        __builtin_nontemporal_store(vfloat4{a0.x, a0.y, a0.z, a0.w}, &orow[lane]);
        __builtin_nontemporal_store(vfloat4{a1.x, a1.y, a1.z, a1.w}, &orow[lane + 64]);
    }

    // ================= query B: select + gather =================
    const int selvB = selectFull();
    a0 = make_float4(-INFINITY, -INFINITY, -INFINITY, -INFINITY);
    a1 = a0;
    #pragma unroll 4
    for (int jj = 0; jj < 32; jj += 2) {
        const int n0 = __builtin_amdgcn_readlane(selvB, jj)     & (NPTS - 1);
        const int n1 = __builtin_amdgcn_readlane(selvB, jj + 1) & (NPTS - 1);
        const float4* r0 = (const float4*)(xb + (size_t)n0 * NF);
        const float4* r1 = (const float4*)(xb + (size_t)n1 * NF);
        const float4 v00 = r0[lane];
        const float4 v01 = r0[lane + 64];
        const float4 v10 = r1[lane];
        const float4 v11 = r1[lane + 64];
        a0.x = fmaxf(fmaxf(a0.x, v00.x), v10.x);
        a0.y = fmaxf(fmaxf(a0.y, v00.y), v10.y);
        a0.z = fmaxf(fmaxf(a0.z, v00.z), v10.z);
        a0.w = fmaxf(fmaxf(a0.w, v00.w), v10.w);
        a1.x = fmaxf(fmaxf(a1.x, v01.x), v11.x);
        a1.y = fmaxf(fmaxf(a1.y, v01.y), v11.y);
        a1.z = fmaxf(fmaxf(a1.z, v01.z), v11.z);
        a1.w = fmaxf(fmaxf(a1.w, v01.w), v11.w);
    }
    {
        vfloat4* orow = (vfloat4*)(out + ((size_t)b * NPTS + iA + 1) * NF);
        __builtin_nontemporal_store(vfloat4{a0.x, a0.y, a0.z, a0.w}, &orow[lane]);
        __builtin_nontemporal_store(vfloat4{a1.x, a1.y, a1.z, a1.w}, &orow[lane + 64]);
    }
}

extern "C" void kernel_launch(void* const* d_in, const int* in_sizes, int n_in,
                              void* d_out, int out_size, void* d_ws, size_t ws_size,
                              hipStream_t stream) {
    const float* x      = (const float*)d_in[0];   // [8, 2048, 512] f32
    const float* points = (const float*)d_in[1];   // [8, 2048, 3]   f32
    float* out          = (float*)d_out;           // [8, 2048, 512] f32

    pointnetpp_knn_maxpool<<<dim3(BATCHES * (NPTS / (BWAVES * QPW))),
                             dim3(256), 0, stream>>>(x, points, out);
}